// Round 15
// baseline (14791.721 us; speedup 1.0000x reference)
//
#include <hip/hip_runtime.h>
#include <math.h>

#define NC 37
#define NW 30
#define NCH 8          // C-chunks (grid.y); partials = NCH*B floats = 2 MB
#define TB 256         // threads per block
#define TPT 2          // batch points per thread

// LDS float offsets for one constituent's weight image (H at 0, P at PBASE)
#define OW1 0
#define OB1 60
#define OW2 90
#define OB2 990
#define OW3 1020
#define OB3 1920
#define OWO 1950
#define OBO 1980
#define PBASE 1984
#define LDSF (2*PBASE)   // 3968 floats = 15872 B

#define REPEAT30(M) M(0) M(1) M(2) M(3) M(4) M(5) M(6) M(7) M(8) M(9) \
                    M(10) M(11) M(12) M(13) M(14) M(15) M(16) M(17) M(18) M(19) \
                    M(20) M(21) M(22) M(23) M(24) M(25) M(26) M(27) M(28) M(29)

#define RELUF(v) fmaxf((v), 0.0f)
#define IDF(v) (v)

// One LDS float2 (two weights, wave-uniform address -> broadcast) feeds
// 4 FMAs: 2 batch points x dual accumulators.
#define R2(k, eA0, eA1, eB0, eB1) { const float2 w_ = wp2_[k]; \
  aA0 = fmaf(w_.x, eA0, aA0); aA1 = fmaf(w_.y, eA1, aA1); \
  aB0 = fmaf(w_.x, eB0, aB0); aB1 = fmaf(w_.y, eB1, aB1); }

#define ROWPAIRS(SA, SB) \
  R2(0,SA##0,SA##1,SB##0,SB##1)     R2(1,SA##2,SA##3,SB##2,SB##3) \
  R2(2,SA##4,SA##5,SB##4,SB##5)     R2(3,SA##6,SA##7,SB##6,SB##7) \
  R2(4,SA##8,SA##9,SB##8,SB##9)     R2(5,SA##10,SA##11,SB##10,SB##11) \
  R2(6,SA##12,SA##13,SB##12,SB##13) R2(7,SA##14,SA##15,SB##14,SB##15) \
  R2(8,SA##16,SA##17,SB##16,SB##17) R2(9,SA##18,SA##19,SB##18,SB##19) \
  R2(10,SA##20,SA##21,SB##20,SB##21) R2(11,SA##22,SA##23,SB##22,SB##23) \
  R2(12,SA##24,SA##25,SB##24,SB##25) R2(13,SA##26,SA##27,SB##26,SB##27) \
  R2(14,SA##28,SA##29,SB##28,SB##29)

// 30-wide neuron for both batch points; weights from LDS (broadcast reads).
#define LROW2(o, WOFF, BOFF, SA, SB, DA, DB, APPLY) { \
  const float2* wp2_ = (const float2*)(Lds + (WOFF) + (o)*NW); \
  const float bb_ = Lds[(BOFF) + (o)]; \
  float aA0 = bb_, aA1 = 0.0f, aB0 = bb_, aB1 = 0.0f; \
  ROWPAIRS(SA, SB) \
  DA = APPLY(aA0 + aA1); DB = APPLY(aB0 + aB1); }

// Layer-1 neuron (Linear(2,-), NO ReLU per reference) for both points.
#define L1ROW2(o, WB) { \
  const float2 w_ = *(const float2*)(Lds + (WB) + OW1 + 2*(o)); \
  const float bb_ = Lds[(WB) + OB1 + (o)]; \
  hA##o = fmaf(w_.x, xA0, fmaf(w_.y, xA1, bb_)); \
  hB##o = fmaf(w_.x, xB0, fmaf(w_.y, xB1, bb_)); }

#define DO_L1H(i) L1ROW2(i, 0)
#define DO_L2H(i) LROW2(i, OW2, OB2, hA, hB, gA##i, gB##i, RELUF)
#define DO_L3H(i) LROW2(i, OW3, OB3, gA, gB, hA##i, hB##i, RELUF)
#define DO_L1P(i) L1ROW2(i, PBASE)
#define DO_L2P(i) LROW2(i, PBASE+OW2, PBASE+OB2, hA, hB, gA##i, gB##i, RELUF)
#define DO_L3P(i) LROW2(i, PBASE+OW3, PBASE+OB3, gA, gB, hA##i, hB##i, RELUF)

// Cooperative, coalesced global->LDS copy (per-lane consecutive addresses).
#define STAGE(off, src, n) for (int i_ = tid; i_ < (n); i_ += TB) Lds[(off)+i_] = (src)[i_];

// Sums the NCH per-chunk partials + bias.
__global__ __launch_bounds__(256) void tide_reduce(const float* __restrict__ ws,
                                                   const float* __restrict__ bias,
                                                   float* __restrict__ out, int B) {
    int b = blockIdx.x * 256 + threadIdx.x;
    if (b >= B) return;
    float s = bias[0];
    #pragma unroll
    for (int k = 0; k < NCH; ++k) s += ws[(long)k * B + b];
    out[b] = s;
}

// Writes bias into every output slot (atomic-fallback mode only).
__global__ __launch_bounds__(256) void tide_init(float* __restrict__ out,
                                                 const float* __restrict__ bias,
                                                 int n) {
    int i = blockIdx.x * 256 + threadIdx.x;
    if (i < n) out[i] = bias[0];
}

// Block (bx, k): chunk k's constituents for 512 batch points (2 per thread).
// Weights staged in LDS per constituent; contributions accumulate in-register.
// MODE 0: partial -> ws[k*B+b]. MODE 1: atomicAdd into out (NCH atomics/b).
template<int MODE>
__global__ __launch_bounds__(256, 3) void tide_main(
    const float* __restrict__ x, const float* __restrict__ a,
    const float* __restrict__ u, const float* __restrict__ f,
    const float* __restrict__ V, const float* __restrict__ t,
    const float* __restrict__ WH1, const float* __restrict__ bH1,
    const float* __restrict__ WH2, const float* __restrict__ bH2,
    const float* __restrict__ WH3, const float* __restrict__ bH3,
    const float* __restrict__ WHo, const float* __restrict__ bHo,
    const float* __restrict__ WP1, const float* __restrict__ bP1,
    const float* __restrict__ WP2, const float* __restrict__ bP2,
    const float* __restrict__ WP3, const float* __restrict__ bP3,
    const float* __restrict__ WPo, const float* __restrict__ bPo,
    float* __restrict__ dst, int B)
{
    __shared__ float Lds[LDSF];
    const int tid = threadIdx.x;
    const int k   = blockIdx.y;
    const int b0  = blockIdx.x * (TB*TPT) + tid;
    const int b1  = b0 + TB;
    const bool ok0 = (b0 < B), ok1 = (b1 < B);

    float xA0=0.f, xA1=0.f, xB0=0.f, xB1=0.f, tb0=0.f, tb1=0.f;
    if (ok0) { const float2 xv = *(const float2*)(x + 2*b0); xA0 = xv.x; xA1 = xv.y; tb0 = t[b0]; }
    if (ok1) { const float2 xv = *(const float2*)(x + 2*b1); xB0 = xv.x; xB1 = xv.y; tb1 = t[b1]; }

#define DECLHA(i) float hA##i; float hB##i;
    REPEAT30(DECLHA)
#define DECLGA(i) float gA##i; float gB##i;
    REPEAT30(DECLGA)

    float heightA = 0.0f, heightB = 0.0f;
    const int cbeg = (k * NC) / NCH;
    const int cend = ((k + 1) * NC) / NCH;

    for (int c = cbeg; c < cend; ++c) {
        __syncthreads();   // protect previous iteration's LDS reads
        STAGE(OW1,        WH1 + c*60,  60)
        STAGE(OB1,        bH1 + c*30,  30)
        STAGE(OW2,        WH2 + c*900, 900)
        STAGE(OB2,        bH2 + c*30,  30)
        STAGE(OW3,        WH3 + c*900, 900)
        STAGE(OB3,        bH3 + c*30,  30)
        STAGE(OWO,        WHo + c*30,  30)
        STAGE(OBO,        bHo + c,     1)
        STAGE(PBASE+OW1,  WP1 + c*60,  60)
        STAGE(PBASE+OB1,  bP1 + c*30,  30)
        STAGE(PBASE+OW2,  WP2 + c*900, 900)
        STAGE(PBASE+OB2,  bP2 + c*30,  30)
        STAGE(PBASE+OW3,  WP3 + c*900, 900)
        STAGE(PBASE+OB3,  bP3 + c*30,  30)
        STAGE(PBASE+OWO,  WPo + c*30,  30)
        STAGE(PBASE+OBO,  bPo + c,     1)
        __syncthreads();

        float HvA, HvB, pvA, pvB;
        // H-MLP (both points)
        REPEAT30(DO_L1H)
        REPEAT30(DO_L2H)
        REPEAT30(DO_L3H)
        LROW2(0, OWO, OBO, hA, hB, HvA, HvB, IDF)
        // P-MLP (both points)
        REPEAT30(DO_L1P)
        REPEAT30(DO_L2P)
        REPEAT30(DO_L3P)
        LROW2(0, PBASE+OWO, PBASE+OBO, hA, hB, pvA, pvB, IDF)

        if (ok0) {
            const long cb = (long)c * B + b0;
            heightA += HvA * f[cb] * cosf(V[cb] + a[cb] * tb0 + u[cb] - pvA);
        }
        if (ok1) {
            const long cb = (long)c * B + b1;
            heightB += HvB * f[cb] * cosf(V[cb] + a[cb] * tb1 + u[cb] - pvB);
        }
    }

    if (MODE == 0) {
        if (ok0) dst[(long)k * B + b0] = heightA;
        if (ok1) dst[(long)k * B + b1] = heightB;
    } else {
        if (ok0) atomicAdd(&dst[b0], heightA);
        if (ok1) atomicAdd(&dst[b1], heightB);
    }
}

extern "C" void kernel_launch(void* const* d_in, const int* in_sizes, int n_in,
                              void* d_out, int out_size, void* d_ws, size_t ws_size,
                              hipStream_t stream) {
    const float* x    = (const float*)d_in[0];
    const float* a    = (const float*)d_in[1];
    const float* u    = (const float*)d_in[2];
    const float* f    = (const float*)d_in[3];
    const float* V    = (const float*)d_in[4];
    const float* t    = (const float*)d_in[5];
    const float* bias = (const float*)d_in[6];
    const float* WH1  = (const float*)d_in[7];
    const float* bH1  = (const float*)d_in[8];
    const float* WH2  = (const float*)d_in[9];
    const float* bH2  = (const float*)d_in[10];
    const float* WH3  = (const float*)d_in[11];
    const float* bH3  = (const float*)d_in[12];
    const float* WHo  = (const float*)d_in[13];
    const float* bHo  = (const float*)d_in[14];
    const float* WP1  = (const float*)d_in[15];
    const float* bP1  = (const float*)d_in[16];
    const float* WP2  = (const float*)d_in[17];
    const float* bP2  = (const float*)d_in[18];
    const float* WP3  = (const float*)d_in[19];
    const float* bP3  = (const float*)d_in[20];
    const float* WPo  = (const float*)d_in[21];
    const float* bPo  = (const float*)d_in[22];
    float* out = (float*)d_out;

    const int B = in_sizes[0] / 2;           // x is [B,2]
    const size_t ws_needed = (size_t)NCH * (size_t)B * sizeof(float);

    dim3 grid((B + TB*TPT - 1) / (TB*TPT), NCH);
    if (ws_size >= ws_needed) {
        float* ws = (float*)d_ws;
        tide_main<0><<<grid, TB, 0, stream>>>(x, a, u, f, V, t,
                                              WH1, bH1, WH2, bH2, WH3, bH3, WHo, bHo,
                                              WP1, bP1, WP2, bP2, WP3, bP3, WPo, bPo,
                                              ws, B);
        tide_reduce<<<(B + 255) / 256, 256, 0, stream>>>(ws, bias, out, B);
    } else {
        tide_init<<<(out_size + 255) / 256, 256, 0, stream>>>(out, bias, out_size);
        tide_main<1><<<grid, TB, 0, stream>>>(x, a, u, f, V, t,
                                              WH1, bH1, WH2, bH2, WH3, bH3, WHo, bHo,
                                              WP1, bP1, WP2, bP2, WP3, bP3, WPo, bPo,
                                              out, B);
    }
}